// Round 1
// baseline (4062.889 us; speedup 1.0000x reference)
//
#include <hip/hip_runtime.h>

#define BS   2048
#define SEQL 288
#define TT   288
#define HH   64
#define NHD  8
#define DHD  8
#define DSZ  29

__device__ __forceinline__ float fast_rcp(float x) { return __builtin_amdgcn_rcpf(x); }
__device__ __forceinline__ float sigmoid_f(float x) { return 1.0f / (1.0f + __expf(-x)); }
__device__ __forceinline__ float tanh_f(float x) {
    // tanh(x) = 1 - 2/(1+exp(2x)); handles +-inf overflow correctly
    return 1.0f - 2.0f / (1.0f + __expf(2.0f * x));
}

__global__ __launch_bounds__(256, 2)
void decoder_kernel(const float* __restrict__ x_dec,
                    const float* __restrict__ enc,
                    const float* __restrict__ hidden,
                    const float* __restrict__ W_ih,
                    const float* __restrict__ W_hh,
                    const float* __restrict__ b_ih,
                    const float* __restrict__ b_hh,
                    const float* __restrict__ Wk,
                    const float* __restrict__ W1,
                    const float* __restrict__ b1,
                    const float* __restrict__ W2,
                    const float* __restrict__ b2,
                    float* __restrict__ out)
{
    __shared__ float WihT[29 * 192];   // [k][g] : W_ih transposed, conflict-free per-lane
    __shared__ float W1T[64 * 32];     // [k][i] : W1 transposed
    __shared__ float Wk_l[64];
    __shared__ float x_l[32];          // padded to 32 (29..31 stay zero)
    __shared__ float h_l[64];
    __shared__ float rz_l[128];
    __shared__ float axn_l[64];
    __shared__ float ahn_l[64];
    __shared__ float qk_l[64];
    __shared__ float ctx_l[64];

    const int tid = threadIdx.x;
    const int b   = blockIdx.x;
    const int hd  = tid >> 5;   // head 0..7
    const int j   = tid & 31;   // lane within head group

    // ---------- one-time loads ----------
    for (int idx = tid; idx < 29 * 192; idx += 256) {
        int k = idx / 192, g = idx - k * 192;
        WihT[idx] = W_ih[g * 29 + k];
    }
    for (int idx = tid; idx < 64 * 32; idx += 256) {
        int k = idx >> 5, i2 = idx & 31;
        W1T[idx] = W1[i2 * 64 + k];
    }
    if (tid < 64) Wk_l[tid] = Wk[tid];
    if (tid < 64) h_l[tid] = hidden[(size_t)b * HH + tid];
    if (tid < 32) x_l[tid] = (tid < 29) ? x_dec[(size_t)b * (TT + 1) * DSZ + tid] : 0.0f;

    // GRU hidden weights: one row per thread (threads 0..191), in registers
    float whh[64];
    if (tid < 192) {
        #pragma unroll
        for (int k = 0; k < 64; ++k) whh[k] = W_hh[tid * 64 + k];
    }
    float bias_rz = 0.f, bias_xn = 0.f, bias_hn = 0.f;
    if (tid < 128)      bias_rz = b_ih[tid] + b_hh[tid];
    else if (tid < 192) { bias_xn = b_ih[tid]; bias_hn = b_hh[tid]; }
    float b1_r = 0.f, w2_r = 0.f, b2_r = 0.f;
    if (tid >= 192 && tid < 224) { b1_r = b1[tid - 192]; w2_r = W2[tid - 192]; }
    if (tid == 192) b2_r = b2[0];

    // encoder values, register resident: v[it][d] = val[b, hd, s=j+32*it, d]
    float v[9][8];
    #pragma unroll
    for (int it = 0; it < 9; ++it) {
        int s = j + 32 * it;
        const float4* p = (const float4*)(enc + ((size_t)s * BS + b) * HH + hd * 8);
        float4 a = p[0], c = p[1];
        v[it][0] = a.x; v[it][1] = a.y; v[it][2] = a.z; v[it][3] = a.w;
        v[it][4] = c.x; v[it][5] = c.y; v[it][6] = c.z; v[it][7] = c.w;
    }
    __syncthreads();

    // ---------- 288 sequential decoder steps ----------
    for (int i = 0; i < TT; ++i) {
        // prefetch next teacher-forcing row (idle lanes of wave 3)
        float xnext = 0.f;
        if (tid >= 224 && tid < 252)
            xnext = x_dec[((size_t)b * (TT + 1) + (i + 1)) * DSZ + (tid - 224)];

        // Phase A: GRU gate pre-activations (192 threads, one gate row each)
        if (tid < 192) {
            float accx = 0.f;
            #pragma unroll
            for (int k = 0; k < 29; ++k) accx += WihT[k * 192 + tid] * x_l[k];
            float acch = 0.f;
            #pragma unroll
            for (int k4 = 0; k4 < 16; ++k4) {
                float4 hh = *(const float4*)&h_l[4 * k4];
                acch += whh[4*k4+0]*hh.x + whh[4*k4+1]*hh.y
                      + whh[4*k4+2]*hh.z + whh[4*k4+3]*hh.w;
            }
            if (tid < 128) rz_l[tid] = sigmoid_f(accx + acch + bias_rz);
            else { axn_l[tid - 128] = accx + bias_xn; ahn_l[tid - 128] = acch + bias_hn; }
        }
        __syncthreads();

        // Phase A2/A3: combine gates -> h_new; fold Wk into query (wave 0 only)
        if (tid < 64) {
            float r = rz_l[tid], z = rz_l[64 + tid];
            float n = tanh_f(axn_l[tid] + r * ahn_l[tid]);
            float hn = (1.0f - z) * n + z * h_l[tid];
            h_l[tid] = hn;
            float qk = 0.f;
            int e = tid & 7, base = tid & 0x38;
            #pragma unroll
            for (int d = 0; d < 8; ++d) {
                float hv = __shfl(hn, base + d, 64);
                qk += hv * Wk_l[d * 8 + e];
            }
            qk_l[tid] = qk;   // qk = q @ Wk  (bk term cancels in softmax)
        }
        __syncthreads();

        // Phase B: single-query attention over 288 encoder positions (all 256 threads)
        float qkr[8];
        {
            float4 q0 = *(const float4*)&qk_l[hd * 8];
            float4 q1 = *(const float4*)&qk_l[hd * 8 + 4];
            qkr[0] = q0.x; qkr[1] = q0.y; qkr[2] = q0.z; qkr[3] = q0.w;
            qkr[4] = q1.x; qkr[5] = q1.y; qkr[6] = q1.z; qkr[7] = q1.w;
        }
        float lg[9];
        #pragma unroll
        for (int it = 0; it < 9; ++it) {
            float sacc = qkr[0] * v[it][0];
            #pragma unroll
            for (int d = 1; d < 8; ++d) sacc += qkr[d] * v[it][d];
            lg[it] = sacc;
        }
        float m = lg[0];
        #pragma unroll
        for (int it = 1; it < 9; ++it) m = fmaxf(m, lg[it]);
        #pragma unroll
        for (int mask = 1; mask <= 16; mask <<= 1) m = fmaxf(m, __shfl_xor(m, mask, 64));

        float esum = 0.f, ctxp[8];
        #pragma unroll
        for (int d = 0; d < 8; ++d) ctxp[d] = 0.f;
        #pragma unroll
        for (int it = 0; it < 9; ++it) {
            float e = __expf(lg[it] - m);
            esum += e;
            #pragma unroll
            for (int d = 0; d < 8; ++d) ctxp[d] += e * v[it][d];
        }
        #pragma unroll
        for (int mask = 1; mask <= 16; mask <<= 1) {
            esum += __shfl_xor(esum, mask, 64);
            #pragma unroll
            for (int d = 0; d < 8; ++d) ctxp[d] += __shfl_xor(ctxp[d], mask, 64);
        }
        if (j == 0) {
            float inv = fast_rcp(esum);
            #pragma unroll
            for (int d = 0; d < 8; ++d) ctx_l[hd * 8 + d] = ctxp[d] * inv;
        }
        __syncthreads();

        // Phase C: MLP head + output + next-step x (wave 3)
        if (tid >= 192 && tid < 224) {
            int i2 = tid - 192;
            float acc = b1_r;
            #pragma unroll
            for (int k4 = 0; k4 < 16; ++k4) {
                float4 cc = *(const float4*)&ctx_l[4 * k4];
                acc += W1T[(4*k4+0)*32 + i2] * cc.x + W1T[(4*k4+1)*32 + i2] * cc.y
                     + W1T[(4*k4+2)*32 + i2] * cc.z + W1T[(4*k4+3)*32 + i2] * cc.w;
            }
            float hid = fmaxf(acc, 0.0f);
            float po = hid * w2_r;
            #pragma unroll
            for (int mask = 1; mask <= 16; mask <<= 1) po += __shfl_xor(po, mask, 64);
            if (i2 == 0) {
                float o = po + b2_r;
                out[(size_t)b * TT + i] = o;
                x_l[28] = o;          // own prediction feeds next step
            }
        }
        if (tid >= 224 && tid < 252) x_l[tid - 224] = xnext;
        __syncthreads();
    }
}

extern "C" void kernel_launch(void* const* d_in, const int* in_sizes, int n_in,
                              void* d_out, int out_size, void* d_ws, size_t ws_size,
                              hipStream_t stream) {
    const float* x_dec  = (const float*)d_in[0];
    const float* enc    = (const float*)d_in[1];
    const float* hidden = (const float*)d_in[2];
    const float* W_ih   = (const float*)d_in[3];
    const float* W_hh   = (const float*)d_in[4];
    const float* b_ih   = (const float*)d_in[5];
    const float* b_hh   = (const float*)d_in[6];
    const float* Wk     = (const float*)d_in[7];
    // d_in[8] = bk : cancels in softmax, unused
    const float* W1     = (const float*)d_in[9];
    const float* b1     = (const float*)d_in[10];
    const float* W2     = (const float*)d_in[11];
    const float* b2     = (const float*)d_in[12];

    decoder_kernel<<<dim3(BS), dim3(256), 0, stream>>>(
        x_dec, enc, hidden, W_ih, W_hh, b_ih, b_hh, Wk, W1, b1, W2, b2,
        (float*)d_out);
}

// Round 2
// 4060.109 us; speedup vs baseline: 1.0007x; 1.0007x over previous
//
#include <hip/hip_runtime.h>

#define BS    2048
#define SEQL  288
#define TT    288
#define HH    64
#define NHD   8
#define DHD   8
#define DSZ   29
#define TEACH 28

__device__ __forceinline__ float rcpf_(float x){ return __builtin_amdgcn_rcpf(x); }
__device__ __forceinline__ float sigm(float x){ return rcpf_(1.0f + __expf(-x)); }
__device__ __forceinline__ float tanhf_(float x){ return 1.0f - 2.0f*rcpf_(1.0f + __expf(2.0f*x)); }

__global__ __launch_bounds__(512, 4)
void decoder_kernel(const float* __restrict__ x_dec,
                    const float* __restrict__ enc,
                    const float* __restrict__ hidden,
                    const float* __restrict__ W_ih,
                    const float* __restrict__ W_hh,
                    const float* __restrict__ b_ih,
                    const float* __restrict__ b_hh,
                    const float* __restrict__ Wk,
                    const float* __restrict__ W1,
                    const float* __restrict__ b1,
                    const float* __restrict__ W2,
                    const float* __restrict__ b2,
                    float* __restrict__ out)
{
    __shared__ float WihT[TEACH*192];   // [k][row], k<28 (col 28 handled via w28_l)
    __shared__ float w28_l[192];
    __shared__ float bcomb[4*64];       // [br | bz | bxn | bhn]
    __shared__ float Wk_l[64];
    __shared__ float W2_l[32], b1_l[32];
    __shared__ float gx_l[192], gh_l[192];
    __shared__ float h_l[64];
    __shared__ float ctx_l[64];
    __shared__ float x_buf[2][TEACH];
    __shared__ float out_l;
    __shared__ float b2_l;
    __shared__ float stage[32][68];     // 68-float stride: 16B aligned rows, conflict-light

    const int tid  = threadIdx.x;
    const int w    = tid >> 6;          // wave index == head
    const int lane = tid & 63;
    const int b    = blockIdx.x;

    // ---------------- one-time parameter staging ----------------
    for (int idx = tid; idx < TEACH*192; idx += 512) {
        int k = idx / 192, row = idx - k*192;
        WihT[idx] = W_ih[row*DSZ + k];
    }
    if (tid < 192) w28_l[tid] = W_ih[tid*DSZ + TEACH];
    if (tid < 64) {
        bcomb[tid]       = b_ih[tid]       + b_hh[tid];
        bcomb[64 + tid]  = b_ih[64 + tid]  + b_hh[64 + tid];
        bcomb[128 + tid] = b_ih[128 + tid];
        bcomb[192 + tid] = b_hh[128 + tid];
        Wk_l[tid] = Wk[tid];
        h_l[tid]  = hidden[(size_t)b*HH + tid];
    }
    if (tid < 32) { W2_l[tid] = W2[tid]; b1_l[tid] = b1[tid]; }
    if (tid < TEACH) x_buf[0][tid] = x_dec[(size_t)b*(TT+1)*DSZ + tid];
    if (tid == 64) out_l = x_dec[(size_t)b*(TT+1)*DSZ + TEACH];
    if (tid == 65) b2_l = b2[0];

    float hprev = hidden[(size_t)b*HH + lane];

    // row weights: waves0-5 hold W_hh half-rows, wave6 holds W1 half-rows (same array!)
    float wrow[32];
    if (tid < 384) {
        int row = tid >> 1, half = tid & 1;
        const float4* p = (const float4*)&W_hh[row*HH + half*32];
        #pragma unroll
        for (int k4 = 0; k4 < 8; ++k4) {
            float4 q = p[k4];
            wrow[4*k4+0]=q.x; wrow[4*k4+1]=q.y; wrow[4*k4+2]=q.z; wrow[4*k4+3]=q.w;
        }
    } else if (tid < 448) {
        int i2 = (tid-384) >> 1, kh = tid & 1;
        const float4* p = (const float4*)&W1[i2*HH + kh*32];
        #pragma unroll
        for (int k4 = 0; k4 < 8; ++k4) {
            float4 q = p[k4];
            wrow[4*k4+0]=q.x; wrow[4*k4+1]=q.y; wrow[4*k4+2]=q.z; wrow[4*k4+3]=q.w;
        }
    }

    // ---------------- encoder values -> registers (coalesced via LDS) ----------------
    // v[t][d] = enc[s = t*64 + lane][b][w*8+d]   (t=4 only for lane<32: s=256+lane)
    float v[5][8];
    #pragma unroll
    for (int c = 0; c < 9; ++c) {
        __syncthreads();
        {
            int row = tid >> 4, cg = tid & 15;
            float4 q = *(const float4*)&enc[((size_t)(c*32 + row)*BS + b)*HH + cg*4];
            *(float4*)&stage[row][cg*4] = q;
        }
        __syncthreads();
        const int t = c >> 1;
        if ((lane >> 5) == (c & 1)) {
            int j31 = lane & 31;
            const float4* sp = (const float4*)&stage[j31][w*8];
            float4 a = sp[0], d4 = sp[1];
            v[t][0]=a.x;  v[t][1]=a.y;  v[t][2]=a.z;  v[t][3]=a.w;
            v[t][4]=d4.x; v[t][5]=d4.y; v[t][6]=d4.z; v[t][7]=d4.w;
        }
    }
    __syncthreads();

    const float* xrow_base = x_dec + (size_t)b*(TT+1)*DSZ;

    // ---------------- 288 sequential steps, 2 barriers each ----------------
    for (int i = 0; i < TT; ++i) {
        // ===== P2: GRU matvecs (waves0-5) || MLP out_{i-1} (wave6) || x prefetch (wave7)
        if (tid < 384) {
            int row = tid >> 1, half = tid & 1;
            float acch = 0.f;
            const float4* hp = (const float4*)&h_l[half*32];
            #pragma unroll
            for (int k4 = 0; k4 < 8; ++k4) {
                float4 hq = hp[k4];
                acch += wrow[4*k4+0]*hq.x + wrow[4*k4+1]*hq.y
                      + wrow[4*k4+2]*hq.z + wrow[4*k4+3]*hq.w;
            }
            float accx = 0.f;
            const float* xb = x_buf[i & 1];
            int kb = half * 14;
            #pragma unroll
            for (int k = 0; k < 14; ++k)
                accx += WihT[(kb + k)*192 + row] * xb[kb + k];
            accx += __shfl_xor(accx, 1, 64);
            acch += __shfl_xor(acch, 1, 64);
            if (half == 0) { gx_l[row] = accx; gh_l[row] = acch; }
        } else if (tid < 448) {
            if (i > 0) {
                int i2 = (tid - 384) >> 1, kh = tid & 1;
                float acc = 0.f;
                const float4* cp = (const float4*)&ctx_l[kh*32];
                #pragma unroll
                for (int k4 = 0; k4 < 8; ++k4) {
                    float4 cq = cp[k4];
                    acc += wrow[4*k4+0]*cq.x + wrow[4*k4+1]*cq.y
                         + wrow[4*k4+2]*cq.z + wrow[4*k4+3]*cq.w;
                }
                acc += __shfl_xor(acc, 1, 64);
                float po = 0.f;
                if (kh == 0) po = fmaxf(acc + b1_l[i2], 0.f) * W2_l[i2];
                #pragma unroll
                for (int mask = 1; mask <= 32; mask <<= 1)
                    po += __shfl_xor(po, mask, 64);
                if (tid == 384) {
                    float o = po + b2_l;
                    out[(size_t)b*TT + (i - 1)] = o;
                    out_l = o;
                }
            }
        } else {
            int l7 = tid - 448;
            if (l7 < TEACH)
                x_buf[(i + 1) & 1][l7] = xrow_base[(size_t)(i + 1)*DSZ + l7];
        }
        __syncthreads();

        // ===== P1: gate combine -> h_new (all waves, replicated) + per-head attention
        float o = out_l;
        float ar  = gx_l[lane]     + gh_l[lane]    + bcomb[lane]      + w28_l[lane]*o;
        float az  = gx_l[64+lane]  + gh_l[64+lane] + bcomb[64+lane]   + w28_l[64+lane]*o;
        float anx = gx_l[128+lane] + bcomb[128+lane] + w28_l[128+lane]*o;
        float anh = gh_l[128+lane] + bcomb[192+lane];
        float r = sigm(ar), z = sigm(az);
        float n = tanhf_(anx + r*anh);
        float hn = (1.f - z)*n + z*hprev;
        hprev = hn;
        if (w == 0) h_l[lane] = hn;

        // qk = q @ Wk  (bk cancels in softmax); per-lane component e of head lane>>3
        float qk = 0.f;
        {
            int base = lane & 0x38, e = lane & 7;
            #pragma unroll
            for (int d = 0; d < 8; ++d)
                qk += __shfl(hn, base + d, 64) * Wk_l[d*8 + e];
        }
        float qkr[8];
        #pragma unroll
        for (int d = 0; d < 8; ++d) qkr[d] = __shfl(qk, ((w & 7) << 3) + d, 64);

        // attention over 288 positions, head = wave; no max-sub (logits bounded)
        float esum = 0.f, ctxp[8];
        #pragma unroll
        for (int d = 0; d < 8; ++d) ctxp[d] = 0.f;
        #pragma unroll
        for (int t = 0; t < 4; ++t) {
            float lg = qkr[0]*v[t][0];
            #pragma unroll
            for (int d = 1; d < 8; ++d) lg += qkr[d]*v[t][d];
            float eE = __expf(lg);
            esum += eE;
            #pragma unroll
            for (int d = 0; d < 8; ++d) ctxp[d] += eE * v[t][d];
        }
        if (lane < 32) {
            float lg = qkr[0]*v[4][0];
            #pragma unroll
            for (int d = 1; d < 8; ++d) lg += qkr[d]*v[4][d];
            float eE = __expf(lg);
            esum += eE;
            #pragma unroll
            for (int d = 0; d < 8; ++d) ctxp[d] += eE * v[4][d];
        }
        // reduce: 3 xor levels on 9 values, component-select, 3 more levels
        #pragma unroll
        for (int mask = 1; mask <= 4; mask <<= 1) {
            esum += __shfl_xor(esum, mask, 64);
            #pragma unroll
            for (int d = 0; d < 8; ++d) ctxp[d] += __shfl_xor(ctxp[d], mask, 64);
        }
        {
            int e = lane & 7;
            float cs = ctxp[0];
            cs = (e == 1) ? ctxp[1] : cs;
            cs = (e == 2) ? ctxp[2] : cs;
            cs = (e == 3) ? ctxp[3] : cs;
            cs = (e == 4) ? ctxp[4] : cs;
            cs = (e == 5) ? ctxp[5] : cs;
            cs = (e == 6) ? ctxp[6] : cs;
            cs = (e == 7) ? ctxp[7] : cs;
            #pragma unroll
            for (int mask = 8; mask <= 32; mask <<= 1) {
                esum += __shfl_xor(esum, mask, 64);
                cs   += __shfl_xor(cs, mask, 64);
            }
            if (lane < 8) ctx_l[w*8 + lane] = cs * rcpf_(esum);
        }
        __syncthreads();
    }

    // ---------------- epilogue: out[287] from ctx_{287} ----------------
    if (tid >= 384 && tid < 448) {
        int i2 = (tid - 384) >> 1, kh = tid & 1;
        float acc = 0.f;
        const float4* cp = (const float4*)&ctx_l[kh*32];
        #pragma unroll
        for (int k4 = 0; k4 < 8; ++k4) {
            float4 cq = cp[k4];
            acc += wrow[4*k4+0]*cq.x + wrow[4*k4+1]*cq.y
                 + wrow[4*k4+2]*cq.z + wrow[4*k4+3]*cq.w;
        }
        acc += __shfl_xor(acc, 1, 64);
        float po = 0.f;
        if (kh == 0) po = fmaxf(acc + b1_l[i2], 0.f) * W2_l[i2];
        #pragma unroll
        for (int mask = 1; mask <= 32; mask <<= 1)
            po += __shfl_xor(po, mask, 64);
        if (tid == 384) out[(size_t)b*TT + (TT - 1)] = po + b2_l;
    }
}

extern "C" void kernel_launch(void* const* d_in, const int* in_sizes, int n_in,
                              void* d_out, int out_size, void* d_ws, size_t ws_size,
                              hipStream_t stream) {
    const float* x_dec  = (const float*)d_in[0];
    const float* enc    = (const float*)d_in[1];
    const float* hidden = (const float*)d_in[2];
    const float* W_ih   = (const float*)d_in[3];
    const float* W_hh   = (const float*)d_in[4];
    const float* b_ih   = (const float*)d_in[5];
    const float* b_hh   = (const float*)d_in[6];
    const float* Wk     = (const float*)d_in[7];
    // d_in[8] = bk : cancels in softmax, unused
    const float* W1     = (const float*)d_in[9];
    const float* b1     = (const float*)d_in[10];
    const float* W2     = (const float*)d_in[11];
    const float* b2     = (const float*)d_in[12];

    decoder_kernel<<<dim3(BS), dim3(512), 0, stream>>>(
        x_dec, enc, hidden, W_ih, W_hh, b_ih, b_hh, Wk, W1, b1, W2, b2,
        (float*)d_out);
}

// Round 4
// 3107.929 us; speedup vs baseline: 1.3073x; 1.3064x over previous
//
#include <hip/hip_runtime.h>

#define BS    2048
#define SEQL  288
#define TT    288
#define HH    64
#define DSZ   29
#define TEACH 28

__device__ __forceinline__ float rcpf_(float x){ return __builtin_amdgcn_rcpf(x); }
__device__ __forceinline__ float sigm(float x){ return rcpf_(1.0f + __expf(-x)); }
__device__ __forceinline__ float tanhf_(float x){ return 1.0f - 2.0f*rcpf_(1.0f + __expf(2.0f*x)); }

// DPP helpers: reductions on the VALU pipe (no ds_bpermute latency chains)
template<int CTRL>
__device__ __forceinline__ float dppadd(float x) {
    int y = __builtin_amdgcn_update_dpp(0, __float_as_int(x), CTRL, 0xF, 0xF, true);
    return x + __int_as_float(y);
}
// full-64-lane sum, result broadcast via readlane(63)
__device__ __forceinline__ float wave_sum(float x) {
    x = dppadd<0x111>(x);   // row_shr:1
    x = dppadd<0x112>(x);   // row_shr:2
    x = dppadd<0x114>(x);   // row_shr:4
    x = dppadd<0x118>(x);   // row_shr:8  -> lane15 of each 16-row = row sum
    x = dppadd<0x142>(x);   // row_bcast:15
    x = dppadd<0x143>(x);   // row_bcast:31 -> lane63 = total
    return __int_as_float(__builtin_amdgcn_readlane(__float_as_int(x), 63));
}
__device__ __forceinline__ float rdlane(float x, int l) {
    return __int_as_float(__builtin_amdgcn_readlane(__float_as_int(x), l));
}

__global__ __launch_bounds__(512, 4)
void decoder_kernel(const float* __restrict__ x_dec,
                    const float* __restrict__ enc,
                    const float* __restrict__ hidden,
                    const float* __restrict__ W_ih,
                    const float* __restrict__ W_hh,
                    const float* __restrict__ b_ih,
                    const float* __restrict__ b_hh,
                    const float* __restrict__ Wk,
                    const float* __restrict__ W1,
                    const float* __restrict__ b1,
                    const float* __restrict__ W2,
                    const float* __restrict__ b2,
                    float* __restrict__ out)
{
    __shared__ float WihT[TEACH*192];     // [k][row], stride-192: conflict-free
    __shared__ float x_pack[TT*TEACH];    // all teacher rows, loaded ONCE (no global in loop)
    __shared__ float stage[32][68];
    __shared__ float g1[128];             // r,z pre-activations (gx+gh+bias)
    __shared__ float2 g2[64];             // n gate: (gx+bxn, gh+bhn)
    __shared__ float h_l[64];
    __shared__ float ctx_l[64];
    __shared__ float out_buf[TT];
    __shared__ float out_l;

    const int tid  = threadIdx.x;
    const int w    = tid >> 6;            // wave = head
    const int lane = tid & 63;
    const int b    = blockIdx.x;

    // ---------------- one-time staging ----------------
    for (int idx = tid; idx < TEACH*192; idx += 512) {
        int k = idx / 192, row = idx - k*192;
        WihT[idx] = W_ih[row*DSZ + k];
    }
    const float* xin_b = x_dec + (size_t)b * (TT+1) * DSZ;
    for (int idx = tid; idx < TT*TEACH; idx += 512) {
        int t = idx / TEACH, k = idx - t*TEACH;
        x_pack[idx] = xin_b[t*DSZ + k];
    }
    if (tid < 64) h_l[tid] = hidden[(size_t)b*HH + tid];
    if (tid == 0) out_l = xin_b[TEACH];   // x[28] of row 0
    float hprev = hidden[(size_t)b*HH + lane];
    const float b2v = b2[0];

    // row weights (all threads define wrow fully -> no divergent-def spills)
    float wrow[32];
    {
        const float* wsrc = (tid < 384) ? &W_hh[(size_t)(tid>>1)*HH + (tid&1)*32]
                          : (tid < 448) ? &W1[(size_t)((tid-384)>>1)*HH + (tid&1)*32]
                                        : &W_hh[(tid&1)*32];
        const float4* p = (const float4*)wsrc;
        #pragma unroll
        for (int k4 = 0; k4 < 8; ++k4) {
            float4 q = p[k4];
            wrow[4*k4+0]=q.x; wrow[4*k4+1]=q.y; wrow[4*k4+2]=q.z; wrow[4*k4+3]=q.w;
        }
    }
    float wkcol[8];
    #pragma unroll
    for (int d = 0; d < 8; ++d) wkcol[d] = Wk[d*8 + (lane & 7)];

    float bias1, bias2;
    {
        int row = (tid < 384) ? (tid>>1) : 0;
        bias1 = (row < 128) ? (b_ih[row] + b_hh[row]) : b_ih[row];
        bias2 = b_hh[row];
    }
    const float w28r = W_ih[lane*DSZ + TEACH];
    const float w28z = W_ih[(64+lane)*DSZ + TEACH];
    const float w28n = W_ih[(128+lane)*DSZ + TEACH];
    const float b1_r = b1[lane >> 1];
    const float w2_r = W2[lane >> 1];

    // encoder values -> registers: v[t][d] = enc[s = 64t + lane][b][w*8+d]
    float v[5][8] = {};
    #pragma unroll
    for (int c = 0; c < 9; ++c) {
        __syncthreads();
        {
            int row = tid >> 4, cg = tid & 15;
            float4 q = *(const float4*)&enc[((size_t)(c*32 + row)*BS + b)*HH + cg*4];
            *(float4*)&stage[row][cg*4] = q;
        }
        __syncthreads();
        const int t = c >> 1;
        const bool mine = ((lane >> 5) == (c & 1));
        int j31 = lane & 31;
        const float4* sp = (const float4*)&stage[j31][w*8];
        float4 a0 = sp[0], a1 = sp[1];
        v[t][0] = mine ? a0.x : v[t][0];
        v[t][1] = mine ? a0.y : v[t][1];
        v[t][2] = mine ? a0.z : v[t][2];
        v[t][3] = mine ? a0.w : v[t][3];
        v[t][4] = mine ? a1.x : v[t][4];
        v[t][5] = mine ? a1.y : v[t][5];
        v[t][6] = mine ? a1.z : v[t][6];
        v[t][7] = mine ? a1.w : v[t][7];
    }
    __syncthreads();

    // ---------------- 288 sequential steps, 2 barriers each, zero global ops ----------------
    for (int i = 0; i < TT; ++i) {
        // ===== P2: GRU matvecs (waves 0-5) || MLP for out_{i-1} (wave 6)
        if (w < 6) {
            const int row  = tid >> 1;      // 0..191
            const int half = tid & 1;
            float accH = 0.f;
            const float4* hp = (const float4*)&h_l[half*32];
            #pragma unroll
            for (int k4 = 0; k4 < 8; ++k4) {
                float4 hq = hp[k4];
                accH += wrow[4*k4+0]*hq.x + wrow[4*k4+1]*hq.y
                      + wrow[4*k4+2]*hq.z + wrow[4*k4+3]*hq.w;
            }
            const int kb = half * 14;
            const float* xp = &x_pack[i*TEACH];
            const float* wp = &WihT[kb*192 + row];
            float accX = 0.f;
            #pragma unroll
            for (int k = 0; k < 14; ++k)
                accX += wp[k*192] * xp[kb + k];
            if (w < 4) {
                float s = dppadd<0xB1>(accH + accX);   // pair combine (quad_perm swap)
                if (half == 0) g1[row] = s + bias1;
            } else {
                float sx = dppadd<0xB1>(accX);
                float sh = dppadd<0xB1>(accH);
                if (half == 0) g2[row - 128] = make_float2(sx + bias1, sh + bias2);
            }
        } else if (w == 6) {
            if (i > 0) {
                int kh = lane & 1;
                float acc = 0.f;
                const float4* cp = (const float4*)&ctx_l[kh*32];
                #pragma unroll
                for (int k4 = 0; k4 < 8; ++k4) {
                    float4 cq = cp[k4];
                    acc += wrow[4*k4+0]*cq.x + wrow[4*k4+1]*cq.y
                         + wrow[4*k4+2]*cq.z + wrow[4*k4+3]*cq.w;
                }
                acc = dppadd<0xB1>(acc);
                float po = (kh == 0) ? fmaxf(acc + b1_r, 0.f) * w2_r : 0.f;
                float tot = wave_sum(po) + b2v;
                if (lane == 0) { out_buf[i-1] = tot; out_l = tot; }
            }
        }
        __syncthreads();

        // ===== P1: gate combine -> h_new (replicated in all waves) + per-head attention
        float o = out_l;
        float ar = g1[lane]      + w28r * o;
        float az = g1[64 + lane] + w28z * o;
        float2 gn = g2[lane];
        float r = sigm(ar), z = sigm(az);
        float n = tanhf_(gn.x + w28n * o + r * gn.y);
        float hn = (1.f - z)*n + z*hprev;
        hprev = hn;
        if (w == 0) h_l[lane] = hn;

        // qk = (q @ Wk): readlane gathers (VALU) — no DS ops
        const int hbase = w * 8;
        float qk = 0.f;
        #pragma unroll
        for (int d = 0; d < 8; ++d)
            qk += rdlane(hn, hbase + d) * wkcol[d];
        float qkr[8];
        #pragma unroll
        for (int e = 0; e < 8; ++e) qkr[e] = rdlane(qk, e);

        // attention over 288 positions (head = wave), no max-sub (logits bounded)
        float esum = 0.f, ctxp[8];
        #pragma unroll
        for (int d = 0; d < 8; ++d) ctxp[d] = 0.f;
        #pragma unroll
        for (int t = 0; t < 4; ++t) {
            float lg = qkr[0]*v[t][0];
            #pragma unroll
            for (int d = 1; d < 8; ++d) lg += qkr[d]*v[t][d];
            float eE = __expf(lg);
            esum += eE;
            #pragma unroll
            for (int d = 0; d < 8; ++d) ctxp[d] += eE * v[t][d];
        }
        if (lane < 32) {
            float lg = qkr[0]*v[4][0];
            #pragma unroll
            for (int d = 1; d < 8; ++d) lg += qkr[d]*v[4][d];
            float eE = __expf(lg);
            esum += eE;
            #pragma unroll
            for (int d = 0; d < 8; ++d) ctxp[d] += eE * v[4][d];
        }
        // reductions on VALU (DPP)
        float esT = wave_sum(esum);
        float c0 = wave_sum(ctxp[0]);
        float c1 = wave_sum(ctxp[1]);
        float c2 = wave_sum(ctxp[2]);
        float c3 = wave_sum(ctxp[3]);
        float c4 = wave_sum(ctxp[4]);
        float c5 = wave_sum(ctxp[5]);
        float c6 = wave_sum(ctxp[6]);
        float c7 = wave_sum(ctxp[7]);
        float myc = c0;
        myc = (lane == 1) ? c1 : myc;
        myc = (lane == 2) ? c2 : myc;
        myc = (lane == 3) ? c3 : myc;
        myc = (lane == 4) ? c4 : myc;
        myc = (lane == 5) ? c5 : myc;
        myc = (lane == 6) ? c6 : myc;
        myc = (lane == 7) ? c7 : myc;
        if (lane < 8) ctx_l[hbase + lane] = myc * rcpf_(esT);
        __syncthreads();
    }

    // ---------------- epilogue: out[287] ----------------
    if (w == 6) {
        int kh = lane & 1;
        float acc = 0.f;
        const float4* cp = (const float4*)&ctx_l[kh*32];
        #pragma unroll
        for (int k4 = 0; k4 < 8; ++k4) {
            float4 cq = cp[k4];
            acc += wrow[4*k4+0]*cq.x + wrow[4*k4+1]*cq.y
                 + wrow[4*k4+2]*cq.z + wrow[4*k4+3]*cq.w;
        }
        acc = dppadd<0xB1>(acc);
        float po = (kh == 0) ? fmaxf(acc + b1_r, 0.f) * w2_r : 0.f;
        float tot = wave_sum(po) + b2v;
        if (lane == 0) out_buf[TT-1] = tot;
    }
    __syncthreads();
    for (int t = tid; t < TT; t += 512)
        out[(size_t)b*TT + t] = out_buf[t];
}

extern "C" void kernel_launch(void* const* d_in, const int* in_sizes, int n_in,
                              void* d_out, int out_size, void* d_ws, size_t ws_size,
                              hipStream_t stream) {
    const float* x_dec  = (const float*)d_in[0];
    const float* enc    = (const float*)d_in[1];
    const float* hidden = (const float*)d_in[2];
    const float* W_ih   = (const float*)d_in[3];
    const float* W_hh   = (const float*)d_in[4];
    const float* b_ih   = (const float*)d_in[5];
    const float* b_hh   = (const float*)d_in[6];
    const float* Wk     = (const float*)d_in[7];
    // d_in[8] = bk : cancels in softmax, unused
    const float* W1     = (const float*)d_in[9];
    const float* b1     = (const float*)d_in[10];
    const float* W2     = (const float*)d_in[11];
    const float* b2     = (const float*)d_in[12];

    decoder_kernel<<<dim3(BS), dim3(512), 0, stream>>>(
        x_dec, enc, hidden, W_ih, W_hh, b_ih, b_hh, Wk, W1, b1, W2, b2,
        (float*)d_out);
}